// Round 1
// baseline (128.436 us; speedup 1.0000x reference)
//
#include <hip/hip_runtime.h>

static constexpr int IMG  = 512;
static constexpr int TILE = 64;

// One diffusion step over a WR x WR region read from `prev` (stride PS = WR+2,
// prev has +1 halo around the region). Region origin in global coords is
// (ty0 - halo, tx0 - halo). Intermediate steps write to LDS `cur` (stride WR),
// forcing out-of-image positions to 0 (zero padding for the next conv).
// Final step (TO_GLOBAL) writes the 64x64 tile to global (always in-image).
template<int WR, int PS, bool TO_GLOBAL>
__device__ __forceinline__ void diffuse_step(
    const float* __restrict__ prev, float* __restrict__ cur,
    const float* __restrict__ Wt, const float* __restrict__ bt,
    int ty0, int tx0, int halo, int tid, float* __restrict__ gout)
{
    for (int idx = tid; idx < WR * WR; idx += 256) {
        const int r = idx / WR;              // compile-time const divisor -> magic mul
        const int c = idx - r * WR;
        const float* p = prev + r * PS + c;
        const float n0 = p[0],      n1 = p[1],      n2 = p[2];
        const float n3 = p[PS],     n4 = p[PS+1],   n5 = p[PS+2];
        const float n6 = p[2*PS],   n7 = p[2*PS+1], n8 = p[2*PS+2];
        float acc = 0.0f;
#pragma unroll
        for (int k = 0; k < 8; ++k) {
            const float* wk = Wt + 9 * k;    // wave-uniform -> s_load, SGPR operand
            float d = bt[k];
            d = fmaf(wk[0], n0, d);
            d = fmaf(wk[1], n1, d);
            d = fmaf(wk[2], n2, d);
            d = fmaf(wk[3], n3, d);
            d = fmaf(wk[4], n4, d);
            d = fmaf(wk[5], n5, d);
            d = fmaf(wk[6], n6, d);
            d = fmaf(wk[7], n7, d);
            d = fmaf(wk[8], n8, d);
            // g(d)*d = exp(-|d|/(1+d^2)) * d ; exp arg in [-0.5, 0] -> benign
            const float t    = fmaf(d, d, 1.0f);
            const float rinv = __builtin_amdgcn_rcpf(t);
            const float e    = __builtin_amdgcn_exp2f(
                                   -1.442695040888963f * __builtin_fabsf(d) * rinv);
            acc = fmaf(e, d, acc);
        }
        float v = n4 - acc * 0.125f;         // in_x - sum_k(features)/K
        if (TO_GLOBAL) {
            const int gy = ty0 + r, gx = tx0 + c;
            gout[gy * IMG + gx] = v;
        } else {
            const int gy = ty0 - halo + r, gx = tx0 - halo + c;
            if (gy < 0 || gy >= IMG || gx < 0 || gx >= IMG) v = 0.0f;
            cur[r * WR + c] = v;
        }
    }
}

__global__ __launch_bounds__(256) void deep_ad_kernel(
    const float* __restrict__ x, const float* __restrict__ W,
    const float* __restrict__ b, float* __restrict__ out)
{
    __shared__ float A[70 * 70];   // X0 input tile (halo 3), later reused for X2 (66x66)
    __shared__ float Bs[68 * 68];  // X1 (halo 2)

    const int tid = threadIdx.x;
    const int tx0 = blockIdx.x * TILE;
    const int ty0 = blockIdx.y * TILE;
    const float* xin  = x   + (size_t)blockIdx.z * (IMG * IMG);
    float*       gout = out + (size_t)blockIdx.z * (IMG * IMG);

    // Stage X0: 70x70 tile with zero padding outside the image.
    for (int idx = tid; idx < 70 * 70; idx += 256) {
        const int r = idx / 70, c = idx - (idx / 70) * 70;
        const int gy = ty0 + r - 3, gx = tx0 + c - 3;
        float v = 0.0f;
        if (gy >= 0 && gy < IMG && gx >= 0 && gx < IMG) v = xin[gy * IMG + gx];
        A[idx] = v;
    }
    __syncthreads();

    diffuse_step<68, 70, false>(A,  Bs, W + 0,   b + 0,  ty0, tx0, 2, tid, nullptr);
    __syncthreads();
    diffuse_step<66, 68, false>(Bs, A,  W + 72,  b + 8,  ty0, tx0, 1, tid, nullptr);
    __syncthreads();
    diffuse_step<64, 66, true >(A, nullptr, W + 144, b + 16, ty0, tx0, 0, tid, gout);
}

extern "C" void kernel_launch(void* const* d_in, const int* in_sizes, int n_in,
                              void* d_out, int out_size, void* d_ws, size_t ws_size,
                              hipStream_t stream)
{
    const float* x = (const float*)d_in[0];
    const float* W = (const float*)d_in[1];  // [3,8,1,3,3] = 216
    const float* b = (const float*)d_in[2];  // [3,8] = 24
    float* out = (float*)d_out;
    const int N = in_sizes[0] / (IMG * IMG); // 16 images
    dim3 grid(IMG / TILE, IMG / TILE, N);
    deep_ad_kernel<<<grid, 256, 0, stream>>>(x, W, b, out);
}